// Round 16
// baseline (228.004 us; speedup 1.0000x reference)
//
#include <hip/hip_runtime.h>

#define B_   2
#define H_   16
#define G_   4
#define S_   2048
#define D_   128
#define I_   2048

#define BM   256
#define TPB  512         // 8 waves: quad q (wave&3) x I-half (wave>>2); 64 q-rows/wave
#define NIT  32          // per half: 32 iters of BN=32 over 1024 i
#define KUT  4096        // one K/U tile: 32x128 f16 = 8 KB
#define VT   8192        // one Vt tile: 128x64 f16 = 16 KB (covers 2 K/U iters)
#define HSTR (3 * 262144)   // ws f16 per kv-head

// K/U swizzle: XOR 16B granule index with (row&15): 16 granules/row -> <=2-way (free).
// Vt: 8 granules/row, (d&7) swizzle, <=2-way. ws image PRE-swizzled; DMA linear.
#define KIDX(r,c) ((r)*128 + ((c) ^ (((r)&15)<<3)))  // Ks/Us: [32][128] f16
#define VIDX(d,c) ((d)*64  + ((c) ^ (((d)&7)<<3)))   // Vt:    [128][64] f16

static constexpr float SCALE = 0.08838834764831845f;  // 1/sqrt(128)

typedef __fp16   p2v  __attribute__((ext_vector_type(2)));
typedef _Float16 h8v  __attribute__((ext_vector_type(8)));
typedef float    f4v  __attribute__((ext_vector_type(4)));
typedef float    f16v __attribute__((ext_vector_type(16)));
typedef int      i4v  __attribute__((ext_vector_type(4)));

__device__ __forceinline__ int pkf16(float a, float b) {
    p2v t = __builtin_amdgcn_cvt_pkrtz(a, b);
    int r; __builtin_memcpy(&r, &t, 4); return r;
}

#define GL_LDS(gp, lp) __builtin_amdgcn_global_load_lds(                      \
    (const __attribute__((address_space(1))) void*)(gp),                      \
    (__attribute__((address_space(3))) void*)(lp), 16, 0, 0)

// ---------------- pre-pass (unchanged from R15): f32 -> f16 tiles, pre-swizzled
// ws per kh: K 64 tiles x 4096 | U 64 tiles x 4096 | V 32 tiles x 8192
__global__ __launch_bounds__(256) void convert_kernel(
    const float* __restrict__ Kg, const float* __restrict__ Ug,
    const float* __restrict__ Vg, _Float16* __restrict__ ws)
{
    const int bid = blockIdx.x;
    const int tid = threadIdx.x;
    __shared__ float vt[64 * 128];
    if (bid < 256) {
        const int kh = bid >> 6, m = (bid >> 5) & 1, it = bid & 31;
        const float* src = (m ? Ug : Kg) + (size_t)kh * I_ * D_ + (size_t)it * 64 * D_;
        _Float16* dstb = ws + (size_t)kh * HSTR + (size_t)m * 262144 + (size_t)it * 2 * KUT;
        const int r   = tid >> 2;
        const int cb  = (tid & 3) * 32;
        const int swz = (r & 15) << 3;
        _Float16* dst = dstb + (size_t)(r >> 5) * KUT + (r & 31) * 128;
#pragma unroll
        for (int g = 0; g < 4; ++g) {
            const int cc0 = cb + g * 8;
            const int d0  = cc0 ^ swz;
            const float4 a = *(const float4*)(src + r * D_ + d0);
            const float4 c = *(const float4*)(src + r * D_ + d0 + 4);
            h8v v; p2v* v2 = (p2v*)&v;
            v2[0] = __builtin_amdgcn_cvt_pkrtz(a.x, a.y);
            v2[1] = __builtin_amdgcn_cvt_pkrtz(a.z, a.w);
            v2[2] = __builtin_amdgcn_cvt_pkrtz(c.x, c.y);
            v2[3] = __builtin_amdgcn_cvt_pkrtz(c.z, c.w);
            *(h8v*)(dst + cc0) = v;
        }
    } else {
        const int v  = bid - 256;
        const int kh = v >> 5, it = v & 31;
        const float* src = Vg + (size_t)kh * I_ * D_ + (size_t)it * 64 * D_;
#pragma unroll
        for (int p = 0; p < 8; ++p) {
            const int idx = p * 256 + tid;
            const int i   = idx >> 5;
            const int d4  = (idx & 31) * 4;
            *(float4*)(&vt[i * 128 + d4]) = *(const float4*)(src + (size_t)i * D_ + d4);
        }
        __syncthreads();
        _Float16* dst = ws + (size_t)kh * HSTR + 2 * 262144 + (size_t)it * VT;
        const int d   = tid >> 1;
        const int cb  = (tid & 1) * 32;
        const int swz = (d & 7) << 3;
#pragma unroll
        for (int g = 0; g < 4; ++g) {
            const int cc0 = cb + g * 8;
            const int ib  = cc0 ^ swz;
            h8v w; p2v* w2 = (p2v*)&w;
#pragma unroll
            for (int pr = 0; pr < 4; ++pr)
                w2[pr] = __builtin_amdgcn_cvt_pkrtz(vt[(ib + 2 * pr) * 128 + d],
                                                    vt[(ib + 2 * pr + 1) * 128 + d]);
            *(h8v*)(dst + d * 64 + cc0) = w;
        }
    }
}

// ---------------- main kernel: 64 q-rows/wave, in-block I-split (halved LDS reads)
__global__ __launch_bounds__(TPB, 2) void flashmlp_kernel(
    const float* __restrict__ Qg, const _Float16* __restrict__ ws,
    float* __restrict__ Og)
{
    // 128 KB LDS, manually carved:
    //   Ks: [half][dbuf][4096] f16 = 32 KB   (offset 0)
    //   Us: [half][dbuf][4096] f16 = 32 KB   (offset 32768)
    //   Vt: [half][dbuf][8192] f16 = 64 KB   (offset 65536)
    // After the loop, the whole buffer is reused as a 32768-f32 exchange (Rx).
    __shared__ __align__(16) char ldsbuf[131072];
    _Float16* Ks = (_Float16*)ldsbuf;
    _Float16* Us = (_Float16*)(ldsbuf + 32768);
    _Float16* Vt = (_Float16*)(ldsbuf + 65536);
    float*    Rx = (float*)ldsbuf;

    // ---- block decode with XCD swizzle: xcd = bid&7 -> kv-head = xcd>>1
    const int bid   = blockIdx.x;
    const int xcd   = bid & 7;
    const int kh    = xcd >> 1;
    const int j     = ((bid >> 3) << 1) | (xcd & 1);   // 0..63 within head
    const int stile = j & 7;           // 8 stiles of 256 rows
    const int bg    = j >> 3;
    const int b     = bg >> 2;
    const int g     = bg & 3;
    const int h     = kh * G_ + g;

    const int tid  = threadIdx.x;
    const int wave = tid >> 6;
    const int wq   = wave & 3;         // q-quad: rows [wq*64, wq*64+64)
    const int wh   = wave >> 2;        // I-half: i in [wh*1024, wh*1024+1024)
    const int lane = tid & 63;
    const int l31  = lane & 31;
    const int hl   = lane >> 5;

    const size_t qbase = ((size_t)(b * H_ + h) * S_ + (size_t)stile * BM) * D_;
    const _Float16* wsK = ws + (size_t)kh * HSTR;
    const _Float16* wsU = wsK + 262144;
    const _Float16* wsV = wsK + 2 * 262144;

    // DMA: each quad stages its own half's tiles; wave covers 1/4 of each tile
    const int soK = wq * 1024 + lane * 8;   // source elem offset in 4096-elem tile
    const int suK = wq * 1024;              // wave-uniform LDS elem offset
    const int soV = wq * 2048 + lane * 8;   // source elem offset in 8192-elem tile
    const int suV = wq * 2048;

    // ---- Q fragments: two 32-row sets (SCALE folded in). 64 VGPR.
    h8v qf[2][8];
#pragma unroll
    for (int qs = 0; qs < 2; ++qs) {
        const float* qp = Qg + qbase + (size_t)(wq * 64 + qs * 32 + l31) * D_;
#pragma unroll
        for (int ks = 0; ks < 8; ++ks) {
            const float4 a = *(const float4*)(qp + ks * 16 + hl * 8);
            const float4 c = *(const float4*)(qp + ks * 16 + hl * 8 + 4);
            h8v v; p2v* v2 = (p2v*)&v;
            v2[0] = __builtin_amdgcn_cvt_pkrtz(a.x * SCALE, a.y * SCALE);
            v2[1] = __builtin_amdgcn_cvt_pkrtz(a.z * SCALE, a.w * SCALE);
            v2[2] = __builtin_amdgcn_cvt_pkrtz(c.x * SCALE, c.y * SCALE);
            v2[3] = __builtin_amdgcn_cvt_pkrtz(c.z * SCALE, c.w * SCALE);
            qf[qs][ks] = v;
        }
    }

    // acc_o[qs][dt]: O^T partial (this wave's I-half); lane col q = wq*64+qs*32+l31,
    // row d = dt*32+(reg&3)+8*(reg>>2)+4*hl. 128 VGPR.
    f16v acc_o[2][4];
#pragma unroll
    for (int qs = 0; qs < 2; ++qs)
#pragma unroll
        for (int dt = 0; dt < 4; ++dt)
#pragma unroll
            for (int e = 0; e < 16; ++e)
                acc_o[qs][dt][e] = 0.f;

    // ---- prologue: DMA this half's K/U tile 0 + V block 0 into buf 0
    {
        const _Float16* kt = wsK + (size_t)(wh * 32) * KUT;
        const _Float16* ut = wsU + (size_t)(wh * 32) * KUT;
        const _Float16* vt = wsV + (size_t)(wh * 16) * VT;
        _Float16* kd = Ks + (wh * 2) * 4096;
        _Float16* ud = Us + (wh * 2) * 4096;
        _Float16* vd = Vt + (wh * 2) * 8192;
        GL_LDS(kt + soK,       kd + suK);
        GL_LDS(kt + soK + 512, kd + suK + 512);
        GL_LDS(ut + soK,       ud + suK);
        GL_LDS(ut + soK + 512, ud + suK + 512);
        GL_LDS(vt + soV,        vd + suV);
        GL_LDS(vt + soV + 512,  vd + suV + 512);
        GL_LDS(vt + soV + 1024, vd + suV + 1024);
        GL_LDS(vt + soV + 1536, vd + suV + 1536);
    }
    __syncthreads();

    for (int it = 0; it < NIT; ++it) {
        const int cur  = it & 1;
        const int vcur = (it >> 1) & 1;
        const _Float16* ksb = Ks + (wh * 2 + cur) * 4096;
        const _Float16* usb = Us + (wh * 2 + cur) * 4096;
        const _Float16* vtb = Vt + (wh * 2 + vcur) * 8192;

        // ---- 1) DMA next tiles for this half; drain for free at end-of-iter barrier
        if (it + 1 < NIT) {
            const int nb = cur ^ 1;
            const _Float16* kt = wsK + (size_t)(wh * 32 + it + 1) * KUT;
            const _Float16* ut = wsU + (size_t)(wh * 32 + it + 1) * KUT;
            _Float16* kd = Ks + (wh * 2 + nb) * 4096;
            _Float16* ud = Us + (wh * 2 + nb) * 4096;
            GL_LDS(kt + soK,       kd + suK);
            GL_LDS(kt + soK + 512, kd + suK + 512);
            GL_LDS(ut + soK,       ud + suK);
            GL_LDS(ut + soK + 512, ud + suK + 512);
        }
        if (!(it & 1) && (it >> 1) + 1 < 16) {
            const int vb = (it >> 1) + 1;
            const _Float16* vt = wsV + (size_t)(wh * 16 + vb) * VT;
            _Float16* vd = Vt + (wh * 2 + (vb & 1)) * 8192;
            GL_LDS(vt + soV,        vd + suV);
            GL_LDS(vt + soV + 512,  vd + suV + 512);
            GL_LDS(vt + soV + 1024, vd + suV + 1024);
            GL_LDS(vt + soV + 1536, vd + suV + 1536);
        }

        // ---- 2) swapped QK: each kf/uf read feeds BOTH q-sets (halved LDS reads)
        f16v am[2], an[2];
#pragma unroll
        for (int qs = 0; qs < 2; ++qs)
#pragma unroll
            for (int e = 0; e < 16; ++e) { am[qs][e] = 0.f; an[qs][e] = 0.f; }
        __builtin_amdgcn_s_setprio(1);
#pragma unroll
        for (int ks = 0; ks < 8; ++ks) {
            const h8v kf = *(const h8v*)(&ksb[KIDX(l31, ks * 16 + hl * 8)]);
            const h8v uf = *(const h8v*)(&usb[KIDX(l31, ks * 16 + hl * 8)]);
            am[0] = __builtin_amdgcn_mfma_f32_32x32x16_f16(kf, qf[0][ks], am[0], 0, 0, 0);
            am[1] = __builtin_amdgcn_mfma_f32_32x32x16_f16(kf, qf[1][ks], am[1], 0, 0, 0);
            an[0] = __builtin_amdgcn_mfma_f32_32x32x16_f16(uf, qf[0][ks], an[0], 0, 0, 0);
            an[1] = __builtin_amdgcn_mfma_f32_32x32x16_f16(uf, qf[1][ks], an[1], 0, 0, 0);
        }
        __builtin_amdgcn_s_setprio(0);

        // ---- 3) gate + pack per q-set; reg r -> i = (r&3)+8*(r>>2)+4*hl
        h8v pb[2][2];
#pragma unroll
        for (int qs = 0; qs < 2; ++qs) {
            int P[8];
#pragma unroll
            for (int p = 0; p < 8; ++p) {
                const float m0 = am[qs][2 * p + 0], n0 = an[qs][2 * p + 0];
                const float m1 = am[qs][2 * p + 1], n1 = an[qs][2 * p + 1];
                const float g0 = m0 * __builtin_amdgcn_rcpf(1.f + __expf(-m0)) * n0;
                const float g1 = m1 * __builtin_amdgcn_rcpf(1.f + __expf(-m1)) * n1;
                P[p] = pkf16(g0, g1);
            }
            auto sA = __builtin_amdgcn_permlane32_swap(P[0], P[2], false, false);
            auto sB = __builtin_amdgcn_permlane32_swap(P[1], P[3], false, false);
            auto sC = __builtin_amdgcn_permlane32_swap(P[4], P[6], false, false);
            auto sD = __builtin_amdgcn_permlane32_swap(P[5], P[7], false, false);
            i4v wlo = i4v{static_cast<int>(sA[0]), static_cast<int>(sB[0]),
                          static_cast<int>(sA[1]), static_cast<int>(sB[1])};
            i4v whi = i4v{static_cast<int>(sC[0]), static_cast<int>(sD[0]),
                          static_cast<int>(sC[1]), static_cast<int>(sD[1])};
            __builtin_memcpy(&pb[qs][0], &wlo, 16);
            __builtin_memcpy(&pb[qs][1], &whi, 16);
        }

        // ---- 4) PV: each va read feeds both q-sets. V tile spans 2 iters.
#pragma unroll
        for (int k2 = 0; k2 < 2; ++k2) {
            const int ks2 = (it & 1) * 2 + k2;
            h8v va[4];
#pragma unroll
            for (int dt = 0; dt < 4; ++dt)
                va[dt] = *(const h8v*)(&vtb[VIDX(dt * 32 + l31, ks2 * 16 + hl * 8)]);
            __builtin_amdgcn_s_setprio(1);
#pragma unroll
            for (int dt = 0; dt < 4; ++dt) {
                acc_o[0][dt] = __builtin_amdgcn_mfma_f32_32x32x16_f16(va[dt], pb[0][k2], acc_o[0][dt], 0, 0, 0);
                acc_o[1][dt] = __builtin_amdgcn_mfma_f32_32x32x16_f16(va[dt], pb[1][k2], acc_o[1][dt], 0, 0, 0);
            }
            __builtin_amdgcn_s_setprio(0);
        }

        // ---- 5) single barrier: DMA drained; buffer reads done
        __syncthreads();
    }

    // ---- epilogue: combine I-halves via LDS (staging buffers are dead now).
    // Coalesced layout: chunk c of thread t lives at Rx[c*1024 + t*4].
    if (wh == 1) {
        const int t = tid & 255;
#pragma unroll
        for (int qs = 0; qs < 2; ++qs)
#pragma unroll
            for (int dt = 0; dt < 4; ++dt)
#pragma unroll
                for (int g4 = 0; g4 < 4; ++g4) {
                    const int c = (qs * 4 + dt) * 4 + g4;
                    f4v v = f4v{acc_o[qs][dt][4 * g4 + 0], acc_o[qs][dt][4 * g4 + 1],
                                acc_o[qs][dt][4 * g4 + 2], acc_o[qs][dt][4 * g4 + 3]};
                    *(f4v*)(&Rx[c * 1024 + t * 4]) = v;
                }
    }
    __syncthreads();
    if (wh == 0) {
        const int t = tid;
#pragma unroll
        for (int qs = 0; qs < 2; ++qs) {
            const int qrow = stile * BM + wq * 64 + qs * 32 + l31;
            float* op = Og + ((size_t)(b * H_ + h) * S_ + qrow) * D_;
#pragma unroll
            for (int dt = 0; dt < 4; ++dt)
#pragma unroll
                for (int g4 = 0; g4 < 4; ++g4) {
                    const int c = (qs * 4 + dt) * 4 + g4;
                    const f4v r = *(const f4v*)(&Rx[c * 1024 + t * 4]);
                    f4v v = f4v{acc_o[qs][dt][4 * g4 + 0] + r[0],
                                acc_o[qs][dt][4 * g4 + 1] + r[1],
                                acc_o[qs][dt][4 * g4 + 2] + r[2],
                                acc_o[qs][dt][4 * g4 + 3] + r[3]};
                    *(f4v*)(op + dt * 32 + g4 * 8 + hl * 4) = v;
                }
        }
    }
}

extern "C" void kernel_launch(void* const* d_in, const int* in_sizes, int n_in,
                              void* d_out, int out_size, void* d_ws, size_t ws_size,
                              hipStream_t stream) {
    const float* Q = (const float*)d_in[0];
    const float* K = (const float*)d_in[1];
    const float* U = (const float*)d_in[2];
    const float* V = (const float*)d_in[3];
    float* out = (float*)d_out;
    _Float16* ws = (_Float16*)d_ws;   // 6.3 MB

    convert_kernel<<<dim3(384), dim3(256), 0, stream>>>(K, U, V, ws);
    flashmlp_kernel<<<dim3((S_ / BM) * B_ * H_), dim3(TPB), 0, stream>>>(Q, ws, out);
}

// Round 17
// 221.597 us; speedup vs baseline: 1.0289x; 1.0289x over previous
//
#include <hip/hip_runtime.h>

#define B_   2
#define H_   16
#define G_   4
#define S_   2048
#define D_   128
#define I_   2048

#define BM   128
#define BN   32          // K/U i-step per iteration
#define TPB  256         // 4 waves x 32 q-rows
#define NIT  (I_ / BN)   // 64
#define KUT  4096        // one K/U tile: 32x128 f16 = 8 KB
#define VT   8192        // one Vt tile: 128x64 f16 = 16 KB (covers 2 K/U iters)
#define HSTR (3 * 262144)   // ws f16 per kv-head

// K/U swizzle: XOR 16B granule index with (row&15): <=2-way (free).
// Vt: (d&7), <=2-way. ws image PRE-swizzled; DMA linear; reads swizzle.
#define KIDX(r,c) ((r)*128 + ((c) ^ (((r)&15)<<3)))  // Ks/Us: [32][128] f16
#define VIDX(d,c) ((d)*64  + ((c) ^ (((d)&7)<<3)))   // Vt:    [128][64] f16

static constexpr float SCALE = 0.08838834764831845f;  // 1/sqrt(128)

typedef __fp16   p2v  __attribute__((ext_vector_type(2)));
typedef _Float16 h8v  __attribute__((ext_vector_type(8)));
typedef float    f4v  __attribute__((ext_vector_type(4)));
typedef float    f16v __attribute__((ext_vector_type(16)));
typedef int      i4v  __attribute__((ext_vector_type(4)));

__device__ __forceinline__ int pkf16(float a, float b) {
    p2v t = __builtin_amdgcn_cvt_pkrtz(a, b);
    int r; __builtin_memcpy(&r, &t, 4); return r;
}

#define GL_LDS(gp, lp) __builtin_amdgcn_global_load_lds(                      \
    (const __attribute__((address_space(1))) void*)(gp),                      \
    (__attribute__((address_space(3))) void*)(lp), 16, 0, 0)

// ---------------- pre-pass (unchanged from R15): f32 -> f16 tiles, pre-swizzled
__global__ __launch_bounds__(256) void convert_kernel(
    const float* __restrict__ Kg, const float* __restrict__ Ug,
    const float* __restrict__ Vg, _Float16* __restrict__ ws)
{
    const int bid = blockIdx.x;
    const int tid = threadIdx.x;
    __shared__ float vt[64 * 128];
    if (bid < 256) {
        const int kh = bid >> 6, m = (bid >> 5) & 1, it = bid & 31;
        const float* src = (m ? Ug : Kg) + (size_t)kh * I_ * D_ + (size_t)it * 64 * D_;
        _Float16* dstb = ws + (size_t)kh * HSTR + (size_t)m * 262144 + (size_t)it * 2 * KUT;
        const int r   = tid >> 2;
        const int cb  = (tid & 3) * 32;
        const int swz = (r & 15) << 3;
        _Float16* dst = dstb + (size_t)(r >> 5) * KUT + (r & 31) * 128;
#pragma unroll
        for (int g = 0; g < 4; ++g) {
            const int cc0 = cb + g * 8;
            const int d0  = cc0 ^ swz;
            const float4 a = *(const float4*)(src + r * D_ + d0);
            const float4 c = *(const float4*)(src + r * D_ + d0 + 4);
            h8v v; p2v* v2 = (p2v*)&v;
            v2[0] = __builtin_amdgcn_cvt_pkrtz(a.x, a.y);
            v2[1] = __builtin_amdgcn_cvt_pkrtz(a.z, a.w);
            v2[2] = __builtin_amdgcn_cvt_pkrtz(c.x, c.y);
            v2[3] = __builtin_amdgcn_cvt_pkrtz(c.z, c.w);
            *(h8v*)(dst + cc0) = v;
        }
    } else {
        const int v  = bid - 256;
        const int kh = v >> 5, it = v & 31;
        const float* src = Vg + (size_t)kh * I_ * D_ + (size_t)it * 64 * D_;
#pragma unroll
        for (int p = 0; p < 8; ++p) {
            const int idx = p * 256 + tid;
            const int i   = idx >> 5;
            const int d4  = (idx & 31) * 4;
            *(float4*)(&vt[i * 128 + d4]) = *(const float4*)(src + (size_t)i * D_ + d4);
        }
        __syncthreads();
        _Float16* dst = ws + (size_t)kh * HSTR + 2 * 262144 + (size_t)it * VT;
        const int d   = tid >> 1;
        const int cb  = (tid & 1) * 32;
        const int swz = (d & 7) << 3;
#pragma unroll
        for (int g = 0; g < 4; ++g) {
            const int cc0 = cb + g * 8;
            const int ib  = cc0 ^ swz;
            h8v w; p2v* w2 = (p2v*)&w;
#pragma unroll
            for (int pr = 0; pr < 4; ++pr)
                w2[pr] = __builtin_amdgcn_cvt_pkrtz(vt[(ib + 2 * pr) * 128 + d],
                                                    vt[(ib + 2 * pr + 1) * 128 + d]);
            *(h8v*)(dst + d * 64 + cc0) = w;
        }
    }
}

// gate(prev) + PV(prev): amP/anP -> pb -> acc. vaP was register-staged last iter.
#define GATE_PV(amP, anP, vaP)                                                \
{                                                                             \
    int P[8];                                                                 \
    _Pragma("unroll")                                                         \
    for (int p = 0; p < 8; ++p) {                                             \
        const float m0 = amP[2*p+0], n0 = anP[2*p+0];                         \
        const float m1 = amP[2*p+1], n1 = anP[2*p+1];                         \
        const float g0 = m0 * __builtin_amdgcn_rcpf(1.f + __expf(-m0)) * n0;  \
        const float g1 = m1 * __builtin_amdgcn_rcpf(1.f + __expf(-m1)) * n1;  \
        P[p] = pkf16(g0, g1);                                                 \
    }                                                                         \
    auto sA_ = __builtin_amdgcn_permlane32_swap(P[0], P[2], false, false);    \
    auto sB_ = __builtin_amdgcn_permlane32_swap(P[1], P[3], false, false);    \
    auto sC_ = __builtin_amdgcn_permlane32_swap(P[4], P[6], false, false);    \
    auto sD_ = __builtin_amdgcn_permlane32_swap(P[5], P[7], false, false);    \
    h8v pb0, pb1;                                                             \
    {                                                                         \
        i4v wlo = i4v{(int)sA_[0], (int)sB_[0], (int)sA_[1], (int)sB_[1]};    \
        i4v whi = i4v{(int)sC_[0], (int)sD_[0], (int)sC_[1], (int)sD_[1]};    \
        __builtin_memcpy(&pb0, &wlo, 16);                                     \
        __builtin_memcpy(&pb1, &whi, 16);                                     \
    }                                                                         \
    __builtin_amdgcn_s_setprio(1);                                            \
    _Pragma("unroll")                                                         \
    for (int dt = 0; dt < 4; ++dt) {                                          \
        acc_o[dt] = __builtin_amdgcn_mfma_f32_32x32x16_f16(vaP[dt],   pb0, acc_o[dt], 0, 0, 0); \
        acc_o[dt] = __builtin_amdgcn_mfma_f32_32x32x16_f16(vaP[4+dt], pb1, acc_o[dt], 0, 0, 0); \
    }                                                                         \
    __builtin_amdgcn_s_setprio(0);                                            \
}

// one pipelined iteration: DMA(T+1); QK(T)->C  ||  gate+PV(T-1) from P; stage vaC(T)
#define FITER(T, amP, anP, vaP, amC, anC, vaC)                                \
{                                                                             \
    const int t_ = (T);                                                       \
    const _Float16* ksb = Ks + (t_ & 1) * KUT;                                \
    const _Float16* usb = Us + (t_ & 1) * KUT;                                \
    const _Float16* vtb = Vt + ((t_ >> 1) & 1) * VT;                          \
    if (t_ + 1 < NIT) {                                                       \
        const int nb = (t_ + 1) & 1;                                          \
        const _Float16* kt = wsK + (size_t)(t_ + 1) * KUT;                    \
        const _Float16* ut = wsU + (size_t)(t_ + 1) * KUT;                    \
        GL_LDS(kt + soK,       Ks + nb * KUT + suK);                          \
        GL_LDS(kt + soK + 512, Ks + nb * KUT + suK + 512);                    \
        GL_LDS(ut + soK,       Us + nb * KUT + suK);                          \
        GL_LDS(ut + soK + 512, Us + nb * KUT + suK + 512);                    \
    }                                                                         \
    if (((t_) & 1) == 0 && (t_ >> 1) + 1 < 32) {                              \
        const int vb = (t_ >> 1) + 1;                                         \
        const _Float16* vtp = wsV + (size_t)vb * VT;                          \
        _Float16* vd = Vt + (vb & 1) * VT;                                    \
        GL_LDS(vtp + soV,        vd + suV);                                   \
        GL_LDS(vtp + soV + 512,  vd + suV + 512);                             \
        GL_LDS(vtp + soV + 1024, vd + suV + 1024);                            \
        GL_LDS(vtp + soV + 1536, vd + suV + 1536);                            \
    }                                                                         \
    _Pragma("unroll")                                                         \
    for (int e = 0; e < 16; ++e) { amC[e] = 0.f; anC[e] = 0.f; }              \
    __builtin_amdgcn_s_setprio(1);                                            \
    _Pragma("unroll")                                                         \
    for (int ks = 0; ks < 8; ++ks) {                                          \
        const h8v kf = *(const h8v*)(&ksb[KIDX(l31, ks * 16 + hl * 8)]);      \
        const h8v uf = *(const h8v*)(&usb[KIDX(l31, ks * 16 + hl * 8)]);      \
        amC = __builtin_amdgcn_mfma_f32_32x32x16_f16(kf, qf[ks], amC, 0, 0, 0); \
        anC = __builtin_amdgcn_mfma_f32_32x32x16_f16(uf, qf[ks], anC, 0, 0, 0); \
    }                                                                         \
    __builtin_amdgcn_s_setprio(0);                                            \
    GATE_PV(amP, anP, vaP);                                                   \
    _Pragma("unroll")                                                         \
    for (int k2 = 0; k2 < 2; ++k2)                                            \
        _Pragma("unroll")                                                     \
        for (int dt = 0; dt < 4; ++dt)                                        \
            vaC[k2 * 4 + dt] = *(const h8v*)(&vtb[VIDX(dt * 32 + l31,         \
                ((t_ & 1) * 2 + k2) * 16 + hl * 8)]);                         \
    __syncthreads();                                                          \
}

// ---------------- main kernel: carried-gate pipeline (QK(t) || gate+PV(t-1))
__global__ __launch_bounds__(TPB, 2) void flashmlp_kernel(
    const float* __restrict__ Qg, const _Float16* __restrict__ ws,
    float* __restrict__ Og)
{
    // LDS: K dbuf 16KB + U dbuf 16KB + Vt dbuf 32KB = 64 KB (2 blocks/CU)
    __shared__ _Float16 Ks[2 * KUT];
    __shared__ _Float16 Us[2 * KUT];
    __shared__ _Float16 Vt[2 * VT];

    // ---- block decode with XCD swizzle: xcd = bid&7 -> kv-head = xcd>>1
    const int bid   = blockIdx.x;
    const int xcd   = bid & 7;
    const int kh    = xcd >> 1;
    const int j     = ((bid >> 3) << 1) | (xcd & 1);   // 0..127 within head
    const int stile = j & 15;          // 16 stiles of 128 rows
    const int bg    = j >> 4;
    const int b     = bg >> 2;
    const int g     = bg & 3;
    const int h     = kh * G_ + g;

    const int tid  = threadIdx.x;
    const int wave = tid >> 6;         // 0..3
    const int lane = tid & 63;
    const int l31  = lane & 31;
    const int hl   = lane >> 5;

    const size_t qbase = ((size_t)(b * H_ + h) * S_ + (size_t)stile * BM) * D_;
    const _Float16* wsK = ws + (size_t)kh * HSTR;
    const _Float16* wsU = wsK + 262144;
    const _Float16* wsV = wsK + 2 * 262144;

    const int soK = wave * 1024 + lane * 8;
    const int suK = wave * 1024;
    const int soV = wave * 2048 + lane * 8;
    const int suV = wave * 2048;

    // ---- Q fragments (SCALE folded in), 32 VGPR
    h8v qf[8];
    {
        const float* qp = Qg + qbase + (size_t)(wave * 32 + l31) * D_;
#pragma unroll
        for (int ks = 0; ks < 8; ++ks) {
            const float4 a = *(const float4*)(qp + ks * 16 + hl * 8);
            const float4 c = *(const float4*)(qp + ks * 16 + hl * 8 + 4);
            h8v v; p2v* v2 = (p2v*)&v;
            v2[0] = __builtin_amdgcn_cvt_pkrtz(a.x * SCALE, a.y * SCALE);
            v2[1] = __builtin_amdgcn_cvt_pkrtz(a.z * SCALE, a.w * SCALE);
            v2[2] = __builtin_amdgcn_cvt_pkrtz(c.x * SCALE, c.y * SCALE);
            v2[3] = __builtin_amdgcn_cvt_pkrtz(c.z * SCALE, c.w * SCALE);
            qf[ks] = v;
        }
    }

    f16v acc_o[4];
#pragma unroll
    for (int dt = 0; dt < 4; ++dt)
#pragma unroll
        for (int e = 0; e < 16; ++e)
            acc_o[dt][e] = 0.f;

    // pipeline register sets
    f16v amA, anA, amB, anB;
    h8v  vaA[8], vaB[8];

    // ---- prologue: DMA tile 0 (K/U) + V block 0; drain at barrier
    {
        GL_LDS(wsK + soK,       Ks + suK);
        GL_LDS(wsK + soK + 512, Ks + suK + 512);
        GL_LDS(wsU + soK,       Us + suK);
        GL_LDS(wsU + soK + 512, Us + suK + 512);
        GL_LDS(wsV + soV,        Vt + suV);
        GL_LDS(wsV + soV + 512,  Vt + suV + 512);
        GL_LDS(wsV + soV + 1024, Vt + suV + 1024);
        GL_LDS(wsV + soV + 1536, Vt + suV + 1536);
    }
    __syncthreads();

    // ---- iter 0 (fill stage): DMA(1) + V block 1; QK(0)->A; stage vaA
    {
        const _Float16* kt = wsK + KUT;
        const _Float16* ut = wsU + KUT;
        GL_LDS(kt + soK,       Ks + KUT + suK);
        GL_LDS(kt + soK + 512, Ks + KUT + suK + 512);
        GL_LDS(ut + soK,       Us + KUT + suK);
        GL_LDS(ut + soK + 512, Us + KUT + suK + 512);
        const _Float16* vtp = wsV + VT;
        GL_LDS(vtp + soV,        Vt + VT + suV);
        GL_LDS(vtp + soV + 512,  Vt + VT + suV + 512);
        GL_LDS(vtp + soV + 1024, Vt + VT + suV + 1024);
        GL_LDS(vtp + soV + 1536, Vt + VT + suV + 1536);

#pragma unroll
        for (int e = 0; e < 16; ++e) { amA[e] = 0.f; anA[e] = 0.f; }
        __builtin_amdgcn_s_setprio(1);
#pragma unroll
        for (int ks = 0; ks < 8; ++ks) {
            const h8v kf = *(const h8v*)(&Ks[KIDX(l31, ks * 16 + hl * 8)]);
            const h8v uf = *(const h8v*)(&Us[KIDX(l31, ks * 16 + hl * 8)]);
            amA = __builtin_amdgcn_mfma_f32_32x32x16_f16(kf, qf[ks], amA, 0, 0, 0);
            anA = __builtin_amdgcn_mfma_f32_32x32x16_f16(uf, qf[ks], anA, 0, 0, 0);
        }
        __builtin_amdgcn_s_setprio(0);
#pragma unroll
        for (int k2 = 0; k2 < 2; ++k2)
#pragma unroll
            for (int dt = 0; dt < 4; ++dt)
                vaA[k2 * 4 + dt] = *(const h8v*)(&Vt[VIDX(dt * 32 + l31,
                    k2 * 16 + hl * 8)]);
        __syncthreads();
    }

    // ---- steady state: pairs keep register sets statically named (rule #20)
    for (int t = 1; t + 1 < NIT; t += 2) {
        FITER(t,     amA, anA, vaA, amB, anB, vaB);
        FITER(t + 1, amB, anB, vaB, amA, anA, vaA);
    }
    FITER(NIT - 1, amA, anA, vaA, amB, anB, vaB);

    // ---- drain: gate + PV of last tile
    GATE_PV(amB, anB, vaB);

    // ---- epilogue: lane owns one q-row; d = dt*32 + g4*8 + hl*4 + (0..3)
    {
        const int qrow = stile * BM + wave * 32 + l31;
        float* op = Og + ((size_t)(b * H_ + h) * S_ + qrow) * D_;
#pragma unroll
        for (int dt = 0; dt < 4; ++dt)
#pragma unroll
            for (int g4 = 0; g4 < 4; ++g4) {
                f4v v = f4v{acc_o[dt][4 * g4 + 0], acc_o[dt][4 * g4 + 1],
                            acc_o[dt][4 * g4 + 2], acc_o[dt][4 * g4 + 3]};
                *(f4v*)(op + dt * 32 + g4 * 8 + hl * 4) = v;
            }
    }
}

extern "C" void kernel_launch(void* const* d_in, const int* in_sizes, int n_in,
                              void* d_out, int out_size, void* d_ws, size_t ws_size,
                              hipStream_t stream) {
    const float* Q = (const float*)d_in[0];
    const float* K = (const float*)d_in[1];
    const float* U = (const float*)d_in[2];
    const float* V = (const float*)d_in[3];
    float* out = (float*)d_out;
    _Float16* ws = (_Float16*)d_ws;   // 6.3 MB

    convert_kernel<<<dim3(384), dim3(256), 0, stream>>>(K, U, V, ws);
    flashmlp_kernel<<<dim3((S_ / BM) * B_ * H_), dim3(TPB), 0, stream>>>(Q, ws, out);
}